// Round 2
// baseline (274.193 us; speedup 1.0000x reference)
//
#include <hip/hip_runtime.h>
#include <hip/hip_bf16.h>

// Problem constants
#define Bsz 4
#define Tseq 2048
#define Cdim 1024
#define NH 16
#define HD 64
#define Mrows (Bsz*Tseq)      // 8192
#define N3C (3*Cdim)          // 3072

typedef __attribute__((ext_vector_type(8))) short short8;
typedef __attribute__((ext_vector_type(4))) short short4v;
typedef __attribute__((ext_vector_type(4))) float float4v;

__device__ __forceinline__ unsigned short f2b(float f) {
    union { float f; unsigned u; } x; x.f = f;
    unsigned u = x.u;
    u += 0x7fff + ((u >> 16) & 1);   // true RNE to bf16
    return (unsigned short)(u >> 16);
}

// pack 2 floats -> bf16x2 dword (RNE)
__device__ __forceinline__ unsigned pk2bf(float a, float b) {
#if __has_builtin(__builtin_amdgcn_cvt_pk_bf16_f32)
    auto w = __builtin_amdgcn_cvt_pk_bf16_f32(a, b);
    unsigned u; __builtin_memcpy(&u, &w, 4);
    return u;
#else
    return (unsigned)f2b(a) | ((unsigned)f2b(b) << 16);
#endif
}

// async global->LDS, 16B per lane; lds dst must be wave-uniform (HW adds lane*16)
#define GLDS(gp, lp) __builtin_amdgcn_global_load_lds(                         \
    (const __attribute__((address_space(1))) unsigned*)(gp),                   \
    (__attribute__((address_space(3))) unsigned*)(lp), 16, 0, 0)

// ---------------- cast x: f32 -> bf16 ----------------
__global__ __launch_bounds__(256) void cast_kernel(const float* __restrict__ in,
                                                   unsigned short* __restrict__ out, int n) {
    int i = (blockIdx.x * 256 + threadIdx.x) * 4;
    if (i < n) {
        float4 v = *reinterpret_cast<const float4*>(in + i);
        ushort4 o;
        o.x = f2b(v.x); o.y = f2b(v.y); o.z = f2b(v.z); o.w = f2b(v.w);
        *reinterpret_cast<ushort4*>(out + i) = o;
    }
}

// ---------------- transpose + cast: W[K][N] f32 -> Wt[N][K] bf16 ----------------
__global__ __launch_bounds__(256) void transpose_cast(const float* __restrict__ in,
                                                      unsigned short* __restrict__ out,
                                                      int K, int N) {
    __shared__ float tile[32][33];
    int n0 = blockIdx.x * 32, k0 = blockIdx.y * 32;
    int tx = threadIdx.x & 31, ty = threadIdx.x >> 5;   // 8 rows per pass
    #pragma unroll
    for (int i = 0; i < 32; i += 8)
        tile[ty + i][tx] = in[(k0 + ty + i) * N + n0 + tx];
    __syncthreads();
    #pragma unroll
    for (int i = 0; i < 32; i += 8)
        out[(size_t)(n0 + ty + i) * K + k0 + tx] = f2b(tile[tx][ty + i]);
}

// ---------------- bf16 MFMA GEMM: C[M,N] = A[M,K] * Bt[N,K]^T ----------------
// 128x128 tile, BK=64, global_load_lds staging, chunk-staggered LDS rows.
// v2: double-buffered LDS, 2-phase pipeline: issue next K-tile's
// global_load_lds BEFORE computing current tile; ONE __syncthreads per
// K-step (its vmcnt(0) drain lands after the ds_read+MFMA work).
// XCD-panel swizzle: XCD x owns row-blocks [8x,8x+8) x all cols.

#define GROW(r) ((r) * 64 + ((r) >> 3) * 8)   // staggered LDS row base (shorts)

template<bool QKV, int NCOL>
__global__ __launch_bounds__(256, 2) void gemm_bt(const unsigned short* __restrict__ A,
                                                  const unsigned short* __restrict__ Bt,
                                                  const float* __restrict__ bias,
                                                  unsigned short* __restrict__ qb,
                                                  unsigned short* __restrict__ kb,
                                                  unsigned short* __restrict__ vb,
                                                  float* __restrict__ out) {
    __shared__ unsigned short As[2][8320];
    __shared__ unsigned short Bs[2][8320];
    int tid = threadIdx.x;
    int lane = tid & 63, wave = tid >> 6;
    int wm = wave >> 1, wn = wave & 1;
    int l15 = lane & 15, quad = lane >> 4;

    // XCD-panel swizzle (blocks dispatch round-robin to XCDs by flat id % 8)
    int f = blockIdx.x;
    int xcd = f & 7, slot = f >> 3;
    int rowblk = xcd * 8 + (slot & 7);   // 64 row-blocks: 8 per XCD
    int colblk = slot >> 3;              // 0..NCOL-1
    int row0 = rowblk * 128;
    int col0 = colblk * 128;

    // staging: wave w covers rows [w*32, w*32+32), 4 chunks of 8 rows;
    // lane l -> row +(l>>3), col (l&7)*8 (16B)
    const unsigned short* Ag = A + (size_t)(row0 + wave * 32 + (lane >> 3)) * Cdim + (lane & 7) * 8;
    const unsigned short* Bg = Bt + (size_t)(col0 + wave * 32 + (lane >> 3)) * Cdim + (lane & 7) * 8;

    float4v acc[4][4] = {};

    // prologue: stage K-tile 0 into buf 0
    {
        unsigned short* Al = &As[0][wave * 2080];
        unsigned short* Bl = &Bs[0][wave * 2080];
        #pragma unroll
        for (int c = 0; c < 4; c++) {
            GLDS(Ag + (size_t)(c * 8) * Cdim, Al + c * 520);
            GLDS(Bg + (size_t)(c * 8) * Cdim, Bl + c * 520);
        }
    }
    __syncthreads();   // drains vmcnt -> tile 0 visible

    int buf = 0;
    for (int k0 = 0; k0 < Cdim; k0 += 64) {
        // issue next tile's staging into buf^1 BEFORE compute (overlap)
        if (k0 + 64 < Cdim) {
            unsigned short* Al = &As[buf ^ 1][wave * 2080];
            unsigned short* Bl = &Bs[buf ^ 1][wave * 2080];
            #pragma unroll
            for (int c = 0; c < 4; c++) {
                GLDS(Ag + (k0 + 64) + (size_t)(c * 8) * Cdim, Al + c * 520);
                GLDS(Bg + (k0 + 64) + (size_t)(c * 8) * Cdim, Bl + c * 520);
            }
        }

        const unsigned short* Asb = &As[buf][0];
        const unsigned short* Bsb = &Bs[buf][0];
        #pragma unroll
        for (int g = 0; g < 2; g++) {
            short8 af[4], bf[4];
            #pragma unroll
            for (int mi = 0; mi < 4; mi++)
                af[mi] = *(const short8*)&Asb[GROW(wm * 64 + mi * 16 + l15) + g * 32 + quad * 8];
            #pragma unroll
            for (int ni = 0; ni < 4; ni++)
                bf[ni] = *(const short8*)&Bsb[GROW(wn * 64 + ni * 16 + l15) + g * 32 + quad * 8];
            #pragma unroll
            for (int mi = 0; mi < 4; mi++)
                #pragma unroll
                for (int ni = 0; ni < 4; ni++)
                    acc[mi][ni] = __builtin_amdgcn_mfma_f32_16x16x32_bf16(af[mi], bf[ni], acc[mi][ni], 0, 0, 0);
        }

        __syncthreads();   // drains vmcnt (next tile staged) + releases buf
        buf ^= 1;
    }

    // epilogue
    #pragma unroll
    for (int mi = 0; mi < 4; mi++) {
        #pragma unroll
        for (int ni = 0; ni < 4; ni++) {
            int colb = col0 + wn * 64 + ni * 16 + l15;
            int rowb = row0 + wm * 64 + mi * 16 + quad * 4;
            if (QKV) {
                int p = colb >> 10;          // 0=q 1=k 2=v
                int h = (colb & 1023) >> 6;
                int d = colb & 63;
                int b = rowb >> 11;
                int t = rowb & 2047;
                if (p == 2) {
                    // V transposed [bh][d][T]: r-values are t-consecutive -> ushort4
                    ushort4 pk;
                    pk.x = f2b(acc[mi][ni][0] + bias[colb]);
                    pk.y = f2b(acc[mi][ni][1] + bias[colb]);
                    pk.z = f2b(acc[mi][ni][2] + bias[colb]);
                    pk.w = f2b(acc[mi][ni][3] + bias[colb]);
                    *(ushort4*)&vb[((size_t)(b * NH + h) * HD + d) * Tseq + t] = pk;
                } else {
                    unsigned short* dst = (p == 0) ? qb : kb;
                    #pragma unroll
                    for (int r = 0; r < 4; r++)
                        dst[((size_t)(b * NH + h) * Tseq + (t + r)) * HD + d] =
                            f2b(acc[mi][ni][r] + bias[colb]);
                }
            } else {
                #pragma unroll
                for (int r = 0; r < 4; r++)
                    out[(size_t)(rowb + r) * Cdim + colb] = acc[mi][ni][r] + bias[colb];
            }
        }
    }
}

// ---------------- flash attention (causal), bf16 MFMA ----------------
// 4-wave blocks (256 thr), q-tile = 128 rows (32/wave), 64-key windows,
// double-buffered K/V LDS with 2-phase pipeline: issue next window's
// global_load_lds BEFORE computing current window; one __syncthreads per
// window (its vmcnt(0) drain lands after ~400 cycles of MFMA+softmax).
// K and V staged via global_load_lds into XOR-swizzled LDS (16B granule
// swizzle g^(row&7)): conflict-free frag reads AND contiguous DMA dst.
// S^T register trick: S^T C-layout == A-operand of mfma 16x16x16bf16_1k.
// Defer-rescale: only rescale O/l when a row max grows by >16 (P <= 2^2.9).

__global__ __launch_bounds__(256, 4) void attn_kernel(const unsigned short* __restrict__ qb,
                                                      const unsigned short* __restrict__ kb,
                                                      const unsigned short* __restrict__ vt,
                                                      unsigned short* __restrict__ yb) {
    __shared__ unsigned short Ks[2][64 * 64];   // [buf][key][64d], swizzled
    __shared__ unsigned short Vs[2][64 * 64];   // [buf][d][64key], swizzled

    int tid = threadIdx.x;
    int lane = tid & 63, wave = tid >> 6;      // 4 waves
    int l15 = lane & 15, quad = lane >> 4;
    int bh = blockIdx.x;                       // head id (fast dim -> XCD grouping)
    int qt = 15 - blockIdx.y;                  // heavy q-tiles dispatch first

    const unsigned short* Qh = qb + (size_t)bh * Tseq * HD;
    const unsigned short* Kh = kb + (size_t)bh * Tseq * HD;
    const unsigned short* Vh = vt + (size_t)bh * HD * Tseq;
    int b = bh >> 4, h = bh & 15;
    const float cexp = 0.18033688011112042f;   // 0.125 * log2(e)

    int q0 = qt * 128;
    int rb0 = q0 + wave * 32;                  // this wave's 32 q-rows

    // Q fragments (B-operand layout: lane holds Q[qrow=l15][d=quad*8+j])
    short8 qf[2][2];
    #pragma unroll
    for (int mi = 0; mi < 2; mi++)
        #pragma unroll
        for (int g = 0; g < 2; g++)
            qf[mi][g] = *(const short8*)(Qh + (size_t)(rb0 + mi * 16 + l15) * HD + g * 32 + quad * 8);

    // staging: whole block stages one 64-key window; wave w covers rows
    // [w*16, w*16+16) of K (key-rows) and of V (d-rows), 2 chunks of 8 rows.
    // lane -> row +(lane>>3), swizzled source granule ((lane&7)^(row&7))*8.
    int srow = lane >> 3;                       // 0..7
    int scol = ((lane & 7) ^ srow) * 8;         // source col (shorts), 16B granule
    const unsigned short* Kg0 = Kh + (size_t)(wave * 16 + srow) * HD + scol;
    const unsigned short* Vg0 = Vh + (size_t)(wave * 16 + srow) * Tseq + scol;
    unsigned short* Kl0 = &Ks[0][wave * 1024];
    unsigned short* Vl0 = &Vs[0][wave * 1024];
    unsigned short* Kl1 = &Ks[1][wave * 1024];
    unsigned short* Vl1 = &Vs[1][wave * 1024];

    // frag-read swizzle constants
    int sx = l15 & 7;
    int kx0 = (quad ^ sx) * 8;                  // K frag col, g=0
    int kx1 = ((4 + quad) ^ sx) * 8;            // K frag col, g=1
    int qh_ = quad >> 1, ql_ = quad & 1;

    float4v ov[2][4] = {};                 // O accs: [16-row blk][d=dg*16+l15], row=quad*4+r
    float m[2]  = {-1e30f, -1e30f};        // running row max (qrow = l15)
    float lp[2] = {0.f, 0.f};              // running row sum of p (qrow = l15)

    int nw = (q0 >> 6) + 2;                // 64-key windows (rows reach q0+127)

    // prologue: stage window 0 -> buf 0
    GLDS(Kg0, Kl0);                GLDS(Kg0 + 8 * HD, Kl0 + 512);
    GLDS(Vg0, Vl0);                GLDS(Vg0 + 8 * Tseq, Vl0 + 512);
    __syncthreads();

    #pragma unroll 1
    for (int it = 0; it < nw; ++it) {
        int j0 = it << 6;

        // issue next window's staging into buf^1 BEFORE compute (overlap)
        if (it + 1 < nw) {
            int jn = j0 + 64;
            unsigned short* Kl = (it & 1) ? Kl0 : Kl1;
            unsigned short* Vl = (it & 1) ? Vl0 : Vl1;
            GLDS(Kg0 + (size_t)jn * HD, Kl);
            GLDS(Kg0 + (size_t)(jn + 8) * HD, Kl + 512);
            GLDS(Vg0 + jn, Vl);
            GLDS(Vg0 + 8 * Tseq + jn, Vl + 512);
        }

        // per-wave skip of fully-masked diagonal windows (barrier still hit)
        if (j0 <= rb0 + 31) {
            const unsigned short* Kl = &Ks[it & 1][0];
            const unsigned short* Vl = &Vs[it & 1][0];

            // S^T = K * Q^T  (C-layout: row=key=quad*4+r, col=qrow=l15)
            float4v st[2][4];
            #pragma unroll
            for (int mi = 0; mi < 2; mi++)
                #pragma unroll
                for (int kg = 0; kg < 4; kg++)
                    st[mi][kg] = (float4v){0.f, 0.f, 0.f, 0.f};
            #pragma unroll
            for (int kg = 0; kg < 4; kg++) {
                int krow = kg * 1024 + l15 * 64;
                short8 kf0 = *(const short8*)&Kl[krow + kx0];
                short8 kf1 = *(const short8*)&Kl[krow + kx1];
                st[0][kg] = __builtin_amdgcn_mfma_f32_16x16x32_bf16(kf0, qf[0][0], st[0][kg], 0, 0, 0);
                st[0][kg] = __builtin_amdgcn_mfma_f32_16x16x32_bf16(kf1, qf[0][1], st[0][kg], 0, 0, 0);
                st[1][kg] = __builtin_amdgcn_mfma_f32_16x16x32_bf16(kf0, qf[1][0], st[1][kg], 0, 0, 0);
                st[1][kg] = __builtin_amdgcn_mfma_f32_16x16x32_bf16(kf1, qf[1][1], st[1][kg], 0, 0, 0);
            }

            // causal mask: only windows overlapping this wave's rows need it
            if (j0 + 63 > rb0) {
                #pragma unroll
                for (int mi = 0; mi < 2; mi++) {
                    int qrow = rb0 + mi * 16 + l15;
                    #pragma unroll
                    for (int kg = 0; kg < 4; kg++) {
                        int keyb = j0 + kg * 16 + quad * 4;
                        #pragma unroll
                        for (int r = 0; r < 4; r++)
                            if (keyb + r > qrow) st[mi][kg][r] = -1e30f;
                    }
                }
            }

            // online softmax with row-max (row = qrow = l15 for st)
            short4v pf[2][4];
            #pragma unroll
            for (int mi = 0; mi < 2; mi++) {
                float mx = st[mi][0][0];
                #pragma unroll
                for (int kg = 0; kg < 4; kg++)
                    #pragma unroll
                    for (int r = 0; r < 4; r++)
                        mx = fmaxf(mx, st[mi][kg][r]);
                mx = fmaxf(mx, __shfl_xor(mx, 16));
                mx = fmaxf(mx, __shfl_xor(mx, 32));
                // defer-rescale: only pay the O/l rescale when max grew by >16
                // (P values then bounded by 2^(16*cexp) ~= 7.4 -- bf16-safe)
                if (__any(mx > m[mi] + 16.0f)) {
                    float mn = fmaxf(m[mi], mx);
                    float alv = __builtin_amdgcn_exp2f((m[mi] - mn) * cexp);
                    m[mi] = mn;
                    lp[mi] *= alv;
                    float ar_[4];
                    #pragma unroll
                    for (int r = 0; r < 4; r++)
                        ar_[r] = __shfl(alv, quad * 4 + r);
                    #pragma unroll
                    for (int dg = 0; dg < 4; dg++)
                        #pragma unroll
                        for (int r = 0; r < 4; r++)
                            ov[mi][dg][r] *= ar_[r];
                }
                float mc = -m[mi] * cexp;    // exp arg = s*cexp + mc (1 fma each)
                float sum = 0.f;
                #pragma unroll
                for (int kg = 0; kg < 4; kg++) {
                    float p0 = __builtin_amdgcn_exp2f(__builtin_fmaf(st[mi][kg][0], cexp, mc));
                    float p1 = __builtin_amdgcn_exp2f(__builtin_fmaf(st[mi][kg][1], cexp, mc));
                    float p2 = __builtin_amdgcn_exp2f(__builtin_fmaf(st[mi][kg][2], cexp, mc));
                    float p3 = __builtin_amdgcn_exp2f(__builtin_fmaf(st[mi][kg][3], cexp, mc));
                    sum += (p0 + p1) + (p2 + p3);
                    union { unsigned u[2]; short4v s; } pk_;
                    pk_.u[0] = pk2bf(p0, p1);
                    pk_.u[1] = pk2bf(p2, p3);
                    pf[mi][kg] = pk_.s;
                }
                lp[mi] += sum;
            }

            // O += P * V  (A = P^T frags from regs, B = V frags from swizzled LDS)
            #pragma unroll
            for (int kg = 0; kg < 4; kg++) {
                int vx = (((kg * 2 + qh_) ^ sx) << 3) + ql_ * 4;
                #pragma unroll
                for (int dg = 0; dg < 4; dg++) {
                    short4v vf = *(const short4v*)&Vl[dg * 1024 + l15 * 64 + vx];
                    ov[0][dg] = __builtin_amdgcn_mfma_f32_16x16x16bf16_1k(pf[0][kg], vf, ov[0][dg], 0, 0, 0);
                    ov[1][dg] = __builtin_amdgcn_mfma_f32_16x16x16bf16_1k(pf[1][kg], vf, ov[1][dg], 0, 0, 0);
                }
            }
        }

        __syncthreads();   // drains vmcnt (next window staged) + releases buf
    }

    // epilogue: reduce l across quads, divide, store y[b][t][h*64+d]
    #pragma unroll
    for (int mi = 0; mi < 2; mi++) {
        float lf = lp[mi];
        lf += __shfl_xor(lf, 16);
        lf += __shfl_xor(lf, 32);          // all lanes: full sum for qrow = l15
        float rinv[4];
        #pragma unroll
        for (int r = 0; r < 4; r++)
            rinv[r] = 1.0f / __shfl(lf, quad * 4 + r);
        #pragma unroll
        for (int dg = 0; dg < 4; dg++)
            #pragma unroll
            for (int r = 0; r < 4; r++) {
                int t = rb0 + mi * 16 + quad * 4 + r;
                yb[((size_t)b * Tseq + t) * Cdim + h * HD + dg * 16 + l15] =
                    f2b(ov[mi][dg][r] * rinv[r]);
            }
    }
}

extern "C" void kernel_launch(void* const* d_in, const int* in_sizes, int n_in,
                              void* d_out, int out_size, void* d_ws, size_t ws_size,
                              hipStream_t stream) {
    const float* x  = (const float*)d_in[0];
    const float* Wa = (const float*)d_in[1];
    const float* ba = (const float*)d_in[2];
    const float* Wp = (const float*)d_in[3];
    const float* bp = (const float*)d_in[4];
    float* out = (float*)d_out;

    unsigned short* ws = (unsigned short*)d_ws;
    unsigned short* xb  = ws;                          // 8192*1024
    unsigned short* Wat = xb  + (size_t)Mrows * Cdim;  // 3072*1024
    unsigned short* Wpt = Wat + (size_t)N3C * Cdim;    // 1024*1024
    unsigned short* qb  = Wpt + (size_t)Cdim * Cdim;   // [bh][T][HD]
    unsigned short* kb  = qb  + (size_t)Bsz * NH * Tseq * HD;   // [bh][T][HD]
    unsigned short* vb  = kb  + (size_t)Bsz * NH * Tseq * HD;   // [bh][HD][T]  (transposed)
    unsigned short* yb  = vb  + (size_t)Bsz * NH * Tseq * HD;

    int nx = Mrows * Cdim;
    cast_kernel<<<nx / 4 / 256, 256, 0, stream>>>(x, xb, nx);
    transpose_cast<<<dim3(N3C / 32, Cdim / 32), 256, 0, stream>>>(Wa, Wat, Cdim, N3C);
    transpose_cast<<<dim3(Cdim / 32, Cdim / 32), 256, 0, stream>>>(Wp, Wpt, Cdim, Cdim);

    gemm_bt<true, 24><<<64 * 24, 256, 0, stream>>>(
        xb, Wat, ba, qb, kb, vb, nullptr);

    attn_kernel<<<dim3(Bsz * NH, 16), 256, 0, stream>>>(qb, kb, vb, yb);

    gemm_bt<false, 8><<<64 * 8, 256, 0, stream>>>(
        yb, Wpt, bp, nullptr, nullptr, nullptr, out);
}

// Round 3
// 265.900 us; speedup vs baseline: 1.0312x; 1.0312x over previous
//
#include <hip/hip_runtime.h>
#include <hip/hip_bf16.h>

// Problem constants
#define Bsz 4
#define Tseq 2048
#define Cdim 1024
#define NH 16
#define HD 64
#define Mrows (Bsz*Tseq)      // 8192
#define N3C (3*Cdim)          // 3072

typedef __attribute__((ext_vector_type(8))) short short8;
typedef __attribute__((ext_vector_type(4))) short short4v;
typedef __attribute__((ext_vector_type(4))) float float4v;

__device__ __forceinline__ unsigned short f2b(float f) {
    union { float f; unsigned u; } x; x.f = f;
    unsigned u = x.u;
    u += 0x7fff + ((u >> 16) & 1);   // true RNE to bf16
    return (unsigned short)(u >> 16);
}

// pack 2 floats -> bf16x2 dword (RNE)
__device__ __forceinline__ unsigned pk2bf(float a, float b) {
#if __has_builtin(__builtin_amdgcn_cvt_pk_bf16_f32)
    auto w = __builtin_amdgcn_cvt_pk_bf16_f32(a, b);
    unsigned u; __builtin_memcpy(&u, &w, 4);
    return u;
#else
    return (unsigned)f2b(a) | ((unsigned)f2b(b) << 16);
#endif
}

// async global->LDS, 16B per lane; lds dst must be wave-uniform (HW adds lane*16)
#define GLDS(gp, lp) __builtin_amdgcn_global_load_lds(                         \
    (const __attribute__((address_space(1))) unsigned*)(gp),                   \
    (__attribute__((address_space(3))) unsigned*)(lp), 16, 0, 0)

// ---------------- cast x: f32 -> bf16 ----------------
__global__ __launch_bounds__(256) void cast_kernel(const float* __restrict__ in,
                                                   unsigned short* __restrict__ out, int n) {
    int i = (blockIdx.x * 256 + threadIdx.x) * 4;
    if (i < n) {
        float4 v = *reinterpret_cast<const float4*>(in + i);
        ushort4 o;
        o.x = f2b(v.x); o.y = f2b(v.y); o.z = f2b(v.z); o.w = f2b(v.w);
        *reinterpret_cast<ushort4*>(out + i) = o;
    }
}

// ---------------- transpose + cast: W[K][N] f32 -> Wt[N][K] bf16 ----------------
__global__ __launch_bounds__(256) void transpose_cast(const float* __restrict__ in,
                                                      unsigned short* __restrict__ out,
                                                      int K, int N) {
    __shared__ float tile[32][33];
    int n0 = blockIdx.x * 32, k0 = blockIdx.y * 32;
    int tx = threadIdx.x & 31, ty = threadIdx.x >> 5;   // 8 rows per pass
    #pragma unroll
    for (int i = 0; i < 32; i += 8)
        tile[ty + i][tx] = in[(k0 + ty + i) * N + n0 + tx];
    __syncthreads();
    #pragma unroll
    for (int i = 0; i < 32; i += 8)
        out[(size_t)(n0 + ty + i) * K + k0 + tx] = f2b(tile[tx][ty + i]);
}

// ---------------- bf16 MFMA GEMM v3: C[M,N] = A[M,K] * Bt[N,K]^T ----------------
// 256x128 tile, BK=64, 512 thr (8 waves, 2M x 4N), TRIPLE-buffered LDS (144KB).
// Counted-vmcnt pipeline: per K-tile, issue 6 global_load_lds staging tile t+2,
// compute tile t (tile t+1 already resident), then s_waitcnt vmcnt(6) + RAW
// s_barrier -- the 6 newest loads (t+2) stay in flight across the barrier; the
// drained oldest 6 are exactly tile t+1's. Never drains to 0 in the loop.
// LDS uses 16B-granule XOR swizzle (g ^ (row&7)), applied on BOTH sides:
// pre-swizzled global source for the linear DMA, swizzled frag-read address.
// Conflict-free ds_read_b128 (2-way max, free).

template<bool QKV>
__global__ __launch_bounds__(512, 2) void gemm256(const unsigned short* __restrict__ A,
                                                  const unsigned short* __restrict__ Bt,
                                                  const float* __restrict__ bias,
                                                  unsigned short* __restrict__ qb,
                                                  unsigned short* __restrict__ kb,
                                                  unsigned short* __restrict__ vb,
                                                  float* __restrict__ out) {
    __shared__ unsigned short As[3][256 * 64];   // 96 KB
    __shared__ unsigned short Bs[3][128 * 64];   // 48 KB

    int tid = threadIdx.x;
    int lane = tid & 63, wave = tid >> 6;        // 8 waves
    int wm = wave >> 2, wn = wave & 3;           // 2M x 4N
    int l15 = lane & 15, quad = lane >> 4;
    int sx = l15 & 7;

    // XCD-panel swizzle: 32 row-blocks, 4 per XCD
    int f = blockIdx.x;
    int xcd = f & 7, slot = f >> 3;
    int rowblk = xcd * 4 + (slot & 3);           // 0..31
    int colblk = slot >> 2;                      // 0..NCOL-1
    int row0 = rowblk * 256;
    int col0 = colblk * 128;

    // staging: lane -> row +(lane>>3), swizzled source granule ((lane&7)^srow)*8
    int srow = lane >> 3;
    int gsw = ((lane & 7) ^ srow) * 8;
    // A: wave stages rows [wave*32, +32) of the 256-row tile (4 chunks of 8)
    // B: wave stages rows [wave*16, +16) of the 128-row tile (2 chunks of 8)
    const unsigned short* Ag = A + (size_t)(row0 + wave * 32 + srow) * Cdim + gsw;
    const unsigned short* Bg = Bt + (size_t)(col0 + wave * 16 + srow) * Cdim + gsw;

    float4v acc[8][2] = {};

    // stage one K-tile (k-offset kk, shorts) into buffer sb: 6 GLDS/thread
    #define STAGE256(kk, sb) do {                                              \
        unsigned short* Al = &As[sb][wave * 32 * 64];                          \
        unsigned short* Bl = &Bs[sb][wave * 16 * 64];                          \
        GLDS(Ag + (kk), Al);                                                   \
        GLDS(Ag + (kk) + (size_t)8  * Cdim, Al + 8 * 64);                      \
        GLDS(Ag + (kk) + (size_t)16 * Cdim, Al + 16 * 64);                     \
        GLDS(Ag + (kk) + (size_t)24 * Cdim, Al + 24 * 64);                     \
        GLDS(Bg + (kk), Bl);                                                   \
        GLDS(Bg + (kk) + (size_t)8  * Cdim, Bl + 8 * 64);                      \
    } while (0)

    // prologue: tiles 0 and 1; wait for tile 0 (6 newest = tile 1 in flight)
    STAGE256(0, 0);
    STAGE256(64, 1);
    asm volatile("s_waitcnt vmcnt(6)" ::: "memory");
    __builtin_amdgcn_s_barrier();

    int bc = 0, bp = 2;                          // compute buf, prefetch buf
    #pragma unroll 1
    for (int t = 0; t < 16; ++t) {
        int kpre = ((t + 2) & 15) * 64;          // wrap tail (re-stages 0,1; benign)
        STAGE256(kpre, bp);

        const unsigned short* Asb = &As[bc][0];
        const unsigned short* Bsb = &Bs[bc][0];
        #pragma unroll
        for (int kg = 0; kg < 2; kg++) {
            int gcol = ((kg * 4 + quad) ^ sx) * 8;
            short8 af[8], bf[2];
            #pragma unroll
            for (int mi = 0; mi < 8; mi++)
                af[mi] = *(const short8*)&Asb[(wm * 128 + mi * 16 + l15) * 64 + gcol];
            #pragma unroll
            for (int ni = 0; ni < 2; ni++)
                bf[ni] = *(const short8*)&Bsb[(wn * 32 + ni * 16 + l15) * 64 + gcol];
            __builtin_amdgcn_s_setprio(1);
            #pragma unroll
            for (int mi = 0; mi < 8; mi++)
                #pragma unroll
                for (int ni = 0; ni < 2; ni++)
                    acc[mi][ni] = __builtin_amdgcn_mfma_f32_16x16x32_bf16(af[mi], bf[ni], acc[mi][ni], 0, 0, 0);
            __builtin_amdgcn_s_setprio(0);
        }

        // counted boundary wait: drain tile t+1's loads, keep tile t+2's 6 in flight
        asm volatile("s_waitcnt vmcnt(6)" ::: "memory");
        __builtin_amdgcn_s_barrier();
        bc = (bc == 2) ? 0 : bc + 1;
        bp = (bp == 2) ? 0 : bp + 1;
    }
    #undef STAGE256

    // epilogue
    #pragma unroll
    for (int mi = 0; mi < 8; mi++) {
        #pragma unroll
        for (int ni = 0; ni < 2; ni++) {
            int colb = col0 + wn * 32 + ni * 16 + l15;
            int rowb = row0 + wm * 128 + mi * 16 + quad * 4;
            if (QKV) {
                int p = colb >> 10;          // 0=q 1=k 2=v
                int h = (colb & 1023) >> 6;
                int d = colb & 63;
                int b = rowb >> 11;
                int t = rowb & 2047;
                if (p == 2) {
                    // V transposed [bh][d][T]: r-values are t-consecutive -> ushort4
                    ushort4 pk;
                    pk.x = f2b(acc[mi][ni][0] + bias[colb]);
                    pk.y = f2b(acc[mi][ni][1] + bias[colb]);
                    pk.z = f2b(acc[mi][ni][2] + bias[colb]);
                    pk.w = f2b(acc[mi][ni][3] + bias[colb]);
                    *(ushort4*)&vb[((size_t)(b * NH + h) * HD + d) * Tseq + t] = pk;
                } else {
                    unsigned short* dst = (p == 0) ? qb : kb;
                    #pragma unroll
                    for (int r = 0; r < 4; r++)
                        dst[((size_t)(b * NH + h) * Tseq + (t + r)) * HD + d] =
                            f2b(acc[mi][ni][r] + bias[colb]);
                }
            } else {
                #pragma unroll
                for (int r = 0; r < 4; r++)
                    out[(size_t)(rowb + r) * Cdim + colb] = acc[mi][ni][r] + bias[colb];
            }
        }
    }
}

// ---------------- flash attention (causal), bf16 MFMA ----------------
// 4-wave blocks (256 thr), q-tile = 128 rows (32/wave), 64-key windows,
// double-buffered K/V LDS with 2-phase pipeline: issue next window's
// global_load_lds BEFORE computing current window; one __syncthreads per
// window (its vmcnt(0) drain lands after ~400 cycles of MFMA+softmax).
// K and V staged via global_load_lds into XOR-swizzled LDS (16B granule
// swizzle g^(row&7)): conflict-free frag reads AND contiguous DMA dst.
// S^T register trick: S^T C-layout == A-operand of mfma 16x16x16bf16_1k.
// Defer-rescale: only rescale O/l when a row max grows by >16 (P <= 2^2.9).

__global__ __launch_bounds__(256, 4) void attn_kernel(const unsigned short* __restrict__ qb,
                                                      const unsigned short* __restrict__ kb,
                                                      const unsigned short* __restrict__ vt,
                                                      unsigned short* __restrict__ yb) {
    __shared__ unsigned short Ks[2][64 * 64];   // [buf][key][64d], swizzled
    __shared__ unsigned short Vs[2][64 * 64];   // [buf][d][64key], swizzled

    int tid = threadIdx.x;
    int lane = tid & 63, wave = tid >> 6;      // 4 waves
    int l15 = lane & 15, quad = lane >> 4;
    int bh = blockIdx.x;                       // head id (fast dim -> XCD grouping)
    int qt = 15 - blockIdx.y;                  // heavy q-tiles dispatch first

    const unsigned short* Qh = qb + (size_t)bh * Tseq * HD;
    const unsigned short* Kh = kb + (size_t)bh * Tseq * HD;
    const unsigned short* Vh = vt + (size_t)bh * HD * Tseq;
    int b = bh >> 4, h = bh & 15;
    const float cexp = 0.18033688011112042f;   // 0.125 * log2(e)

    int q0 = qt * 128;
    int rb0 = q0 + wave * 32;                  // this wave's 32 q-rows

    // Q fragments (B-operand layout: lane holds Q[qrow=l15][d=quad*8+j])
    short8 qf[2][2];
    #pragma unroll
    for (int mi = 0; mi < 2; mi++)
        #pragma unroll
        for (int g = 0; g < 2; g++)
            qf[mi][g] = *(const short8*)(Qh + (size_t)(rb0 + mi * 16 + l15) * HD + g * 32 + quad * 8);

    // staging: whole block stages one 64-key window; wave w covers rows
    // [w*16, w*16+16) of K (key-rows) and of V (d-rows), 2 chunks of 8 rows.
    // lane -> row +(lane>>3), swizzled source granule ((lane&7)^(row&7))*8.
    int srow = lane >> 3;                       // 0..7
    int scol = ((lane & 7) ^ srow) * 8;         // source col (shorts), 16B granule
    const unsigned short* Kg0 = Kh + (size_t)(wave * 16 + srow) * HD + scol;
    const unsigned short* Vg0 = Vh + (size_t)(wave * 16 + srow) * Tseq + scol;
    unsigned short* Kl0 = &Ks[0][wave * 1024];
    unsigned short* Vl0 = &Vs[0][wave * 1024];
    unsigned short* Kl1 = &Ks[1][wave * 1024];
    unsigned short* Vl1 = &Vs[1][wave * 1024];

    // frag-read swizzle constants
    int sx = l15 & 7;
    int kx0 = (quad ^ sx) * 8;                  // K frag col, g=0
    int kx1 = ((4 + quad) ^ sx) * 8;            // K frag col, g=1
    int qh_ = quad >> 1, ql_ = quad & 1;

    float4v ov[2][4] = {};                 // O accs: [16-row blk][d=dg*16+l15], row=quad*4+r
    float m[2]  = {-1e30f, -1e30f};        // running row max (qrow = l15)
    float lp[2] = {0.f, 0.f};              // running row sum of p (qrow = l15)

    int nw = (q0 >> 6) + 2;                // 64-key windows (rows reach q0+127)

    // prologue: stage window 0 -> buf 0
    GLDS(Kg0, Kl0);                GLDS(Kg0 + 8 * HD, Kl0 + 512);
    GLDS(Vg0, Vl0);                GLDS(Vg0 + 8 * Tseq, Vl0 + 512);
    __syncthreads();

    #pragma unroll 1
    for (int it = 0; it < nw; ++it) {
        int j0 = it << 6;

        // issue next window's staging into buf^1 BEFORE compute (overlap)
        if (it + 1 < nw) {
            int jn = j0 + 64;
            unsigned short* Kl = (it & 1) ? Kl0 : Kl1;
            unsigned short* Vl = (it & 1) ? Vl0 : Vl1;
            GLDS(Kg0 + (size_t)jn * HD, Kl);
            GLDS(Kg0 + (size_t)(jn + 8) * HD, Kl + 512);
            GLDS(Vg0 + jn, Vl);
            GLDS(Vg0 + 8 * Tseq + jn, Vl + 512);
        }

        // per-wave skip of fully-masked diagonal windows (barrier still hit)
        if (j0 <= rb0 + 31) {
            const unsigned short* Kl = &Ks[it & 1][0];
            const unsigned short* Vl = &Vs[it & 1][0];

            // S^T = K * Q^T  (C-layout: row=key=quad*4+r, col=qrow=l15)
            float4v st[2][4];
            #pragma unroll
            for (int mi = 0; mi < 2; mi++)
                #pragma unroll
                for (int kg = 0; kg < 4; kg++)
                    st[mi][kg] = (float4v){0.f, 0.f, 0.f, 0.f};
            #pragma unroll
            for (int kg = 0; kg < 4; kg++) {
                int krow = kg * 1024 + l15 * 64;
                short8 kf0 = *(const short8*)&Kl[krow + kx0];
                short8 kf1 = *(const short8*)&Kl[krow + kx1];
                st[0][kg] = __builtin_amdgcn_mfma_f32_16x16x32_bf16(kf0, qf[0][0], st[0][kg], 0, 0, 0);
                st[0][kg] = __builtin_amdgcn_mfma_f32_16x16x32_bf16(kf1, qf[0][1], st[0][kg], 0, 0, 0);
                st[1][kg] = __builtin_amdgcn_mfma_f32_16x16x32_bf16(kf0, qf[1][0], st[1][kg], 0, 0, 0);
                st[1][kg] = __builtin_amdgcn_mfma_f32_16x16x32_bf16(kf1, qf[1][1], st[1][kg], 0, 0, 0);
            }

            // causal mask: only windows overlapping this wave's rows need it
            if (j0 + 63 > rb0) {
                #pragma unroll
                for (int mi = 0; mi < 2; mi++) {
                    int qrow = rb0 + mi * 16 + l15;
                    #pragma unroll
                    for (int kg = 0; kg < 4; kg++) {
                        int keyb = j0 + kg * 16 + quad * 4;
                        #pragma unroll
                        for (int r = 0; r < 4; r++)
                            if (keyb + r > qrow) st[mi][kg][r] = -1e30f;
                    }
                }
            }

            // online softmax with row-max (row = qrow = l15 for st)
            short4v pf[2][4];
            #pragma unroll
            for (int mi = 0; mi < 2; mi++) {
                float mx = st[mi][0][0];
                #pragma unroll
                for (int kg = 0; kg < 4; kg++)
                    #pragma unroll
                    for (int r = 0; r < 4; r++)
                        mx = fmaxf(mx, st[mi][kg][r]);
                mx = fmaxf(mx, __shfl_xor(mx, 16));
                mx = fmaxf(mx, __shfl_xor(mx, 32));
                // defer-rescale: only pay the O/l rescale when max grew by >16
                // (P values then bounded by 2^(16*cexp) ~= 7.4 -- bf16-safe)
                if (__any(mx > m[mi] + 16.0f)) {
                    float mn = fmaxf(m[mi], mx);
                    float alv = __builtin_amdgcn_exp2f((m[mi] - mn) * cexp);
                    m[mi] = mn;
                    lp[mi] *= alv;
                    float ar_[4];
                    #pragma unroll
                    for (int r = 0; r < 4; r++)
                        ar_[r] = __shfl(alv, quad * 4 + r);
                    #pragma unroll
                    for (int dg = 0; dg < 4; dg++)
                        #pragma unroll
                        for (int r = 0; r < 4; r++)
                            ov[mi][dg][r] *= ar_[r];
                }
                float mc = -m[mi] * cexp;    // exp arg = s*cexp + mc (1 fma each)
                float sum = 0.f;
                #pragma unroll
                for (int kg = 0; kg < 4; kg++) {
                    float p0 = __builtin_amdgcn_exp2f(__builtin_fmaf(st[mi][kg][0], cexp, mc));
                    float p1 = __builtin_amdgcn_exp2f(__builtin_fmaf(st[mi][kg][1], cexp, mc));
                    float p2 = __builtin_amdgcn_exp2f(__builtin_fmaf(st[mi][kg][2], cexp, mc));
                    float p3 = __builtin_amdgcn_exp2f(__builtin_fmaf(st[mi][kg][3], cexp, mc));
                    sum += (p0 + p1) + (p2 + p3);
                    union { unsigned u[2]; short4v s; } pk_;
                    pk_.u[0] = pk2bf(p0, p1);
                    pk_.u[1] = pk2bf(p2, p3);
                    pf[mi][kg] = pk_.s;
                }
                lp[mi] += sum;
            }

            // O += P * V  (A = P^T frags from regs, B = V frags from swizzled LDS)
            #pragma unroll
            for (int kg = 0; kg < 4; kg++) {
                int vx = (((kg * 2 + qh_) ^ sx) << 3) + ql_ * 4;
                #pragma unroll
                for (int dg = 0; dg < 4; dg++) {
                    short4v vf = *(const short4v*)&Vl[dg * 1024 + l15 * 64 + vx];
                    ov[0][dg] = __builtin_amdgcn_mfma_f32_16x16x16bf16_1k(pf[0][kg], vf, ov[0][dg], 0, 0, 0);
                    ov[1][dg] = __builtin_amdgcn_mfma_f32_16x16x16bf16_1k(pf[1][kg], vf, ov[1][dg], 0, 0, 0);
                }
            }
        }

        __syncthreads();   // drains vmcnt (next window staged) + releases buf
    }

    // epilogue: reduce l across quads, divide, store y[b][t][h*64+d]
    #pragma unroll
    for (int mi = 0; mi < 2; mi++) {
        float lf = lp[mi];
        lf += __shfl_xor(lf, 16);
        lf += __shfl_xor(lf, 32);          // all lanes: full sum for qrow = l15
        float rinv[4];
        #pragma unroll
        for (int r = 0; r < 4; r++)
            rinv[r] = 1.0f / __shfl(lf, quad * 4 + r);
        #pragma unroll
        for (int dg = 0; dg < 4; dg++)
            #pragma unroll
            for (int r = 0; r < 4; r++) {
                int t = rb0 + mi * 16 + quad * 4 + r;
                yb[((size_t)b * Tseq + t) * Cdim + h * HD + dg * 16 + l15] =
                    f2b(ov[mi][dg][r] * rinv[r]);
            }
    }
}

extern "C" void kernel_launch(void* const* d_in, const int* in_sizes, int n_in,
                              void* d_out, int out_size, void* d_ws, size_t ws_size,
                              hipStream_t stream) {
    const float* x  = (const float*)d_in[0];
    const float* Wa = (const float*)d_in[1];
    const float* ba = (const float*)d_in[2];
    const float* Wp = (const float*)d_in[3];
    const float* bp = (const float*)d_in[4];
    float* out = (float*)d_out;

    unsigned short* ws = (unsigned short*)d_ws;
    unsigned short* xb  = ws;                          // 8192*1024
    unsigned short* Wat = xb  + (size_t)Mrows * Cdim;  // 3072*1024
    unsigned short* Wpt = Wat + (size_t)N3C * Cdim;    // 1024*1024
    unsigned short* qb  = Wpt + (size_t)Cdim * Cdim;   // [bh][T][HD]
    unsigned short* kb  = qb  + (size_t)Bsz * NH * Tseq * HD;   // [bh][T][HD]
    unsigned short* vb  = kb  + (size_t)Bsz * NH * Tseq * HD;   // [bh][HD][T]  (transposed)
    unsigned short* yb  = vb  + (size_t)Bsz * NH * Tseq * HD;

    int nx = Mrows * Cdim;
    cast_kernel<<<nx / 4 / 256, 256, 0, stream>>>(x, xb, nx);
    transpose_cast<<<dim3(N3C / 32, Cdim / 32), 256, 0, stream>>>(Wa, Wat, Cdim, N3C);
    transpose_cast<<<dim3(Cdim / 32, Cdim / 32), 256, 0, stream>>>(Wp, Wpt, Cdim, Cdim);

    // QKV: 32 rowblks x 24 colblks = 768 blocks
    gemm256<true><<<768, 512, 0, stream>>>(xb, Wat, ba, qb, kb, vb, nullptr);

    attn_kernel<<<dim3(Bsz * NH, 16), 256, 0, stream>>>(qb, kb, vb, yb);

    // proj: 32 rowblks x 8 colblks = 256 blocks
    gemm256<false><<<256, 512, 0, stream>>>(yb, Wpt, bp, nullptr, nullptr, nullptr, out);
}

// Round 4
// 256.452 us; speedup vs baseline: 1.0692x; 1.0368x over previous
//
#include <hip/hip_runtime.h>
#include <hip/hip_bf16.h>

// Problem constants
#define Bsz 4
#define Tseq 2048
#define Cdim 1024
#define NH 16
#define HD 64
#define Mrows (Bsz*Tseq)      // 8192
#define N3C (3*Cdim)          // 3072

typedef __attribute__((ext_vector_type(8))) short short8;
typedef __attribute__((ext_vector_type(4))) short short4v;
typedef __attribute__((ext_vector_type(4))) float float4v;

__device__ __forceinline__ unsigned short f2b(float f) {
    union { float f; unsigned u; } x; x.f = f;
    unsigned u = x.u;
    u += 0x7fff + ((u >> 16) & 1);   // true RNE to bf16
    return (unsigned short)(u >> 16);
}

// pack 2 floats -> bf16x2 dword (RNE)
__device__ __forceinline__ unsigned pk2bf(float a, float b) {
#if __has_builtin(__builtin_amdgcn_cvt_pk_bf16_f32)
    auto w = __builtin_amdgcn_cvt_pk_bf16_f32(a, b);
    unsigned u; __builtin_memcpy(&u, &w, 4);
    return u;
#else
    return (unsigned)f2b(a) | ((unsigned)f2b(b) << 16);
#endif
}

// async global->LDS, 16B per lane; lds dst must be wave-uniform (HW adds lane*16)
#define GLDS(gp, lp) __builtin_amdgcn_global_load_lds(                         \
    (const __attribute__((address_space(1))) unsigned*)(gp),                   \
    (__attribute__((address_space(3))) unsigned*)(lp), 16, 0, 0)

// ---------------- cast x: f32 -> bf16 ----------------
__global__ __launch_bounds__(256) void cast_kernel(const float* __restrict__ in,
                                                   unsigned short* __restrict__ out, int n) {
    int i = (blockIdx.x * 256 + threadIdx.x) * 4;
    if (i < n) {
        float4 v = *reinterpret_cast<const float4*>(in + i);
        ushort4 o;
        o.x = f2b(v.x); o.y = f2b(v.y); o.z = f2b(v.z); o.w = f2b(v.w);
        *reinterpret_cast<ushort4*>(out + i) = o;
    }
}

// ---------------- transpose + cast: W[K][N] f32 -> Wt[N][K] bf16 ----------------
__global__ __launch_bounds__(256) void transpose_cast(const float* __restrict__ in,
                                                      unsigned short* __restrict__ out,
                                                      int K, int N) {
    __shared__ float tile[32][33];
    int n0 = blockIdx.x * 32, k0 = blockIdx.y * 32;
    int tx = threadIdx.x & 31, ty = threadIdx.x >> 5;   // 8 rows per pass
    #pragma unroll
    for (int i = 0; i < 32; i += 8)
        tile[ty + i][tx] = in[(k0 + ty + i) * N + n0 + tx];
    __syncthreads();
    #pragma unroll
    for (int i = 0; i < 32; i += 8)
        out[(size_t)(n0 + ty + i) * K + k0 + tx] = f2b(tile[tx][ty + i]);
}

// ================ bf16 MFMA GEMM, 8-phase 256x256 (QKV) ================
// BM=BN=256, BK=64, 512 thr (8 waves, 2M x 4N -> wave tile 128x64).
// Double-buffered LDS (128 KiB), per K-tile 4 phases:
//   {ds_read subtile || stage 1 half-tile (2 GLDS)} -> barrier ->
//   lgkmcnt(0)+sched_barrier -> setprio(1) 16xMFMA setprio(0) -> barrier
// Stage order of tile t+1: [A0, A1, B0, B1].  Counted waits only:
//   vmcnt(4) at phase1 (drains B1(t) before t.p2 reads it; newest-2 halves
//   A0,A1(t+1) stay in flight), vmcnt(2) at phase3 (drains A0,A1,B0(t+1)
//   for t+1.p0; newest half B1(t+1) stays in flight). Never 0 in the loop.
// Both-sides 16B-granule XOR swizzle (g ^ (row&7)): linear DMA dst with
// pre-swizzled global source; swizzled frag reads -> conflict-free b128.

template<bool QKV>
__global__ __launch_bounds__(512, 2) void gemm8p(const unsigned short* __restrict__ A,
                                                 const unsigned short* __restrict__ Bt,
                                                 const float* __restrict__ bias,
                                                 unsigned short* __restrict__ qb,
                                                 unsigned short* __restrict__ kb,
                                                 unsigned short* __restrict__ vb,
                                                 float* __restrict__ out) {
    __shared__ unsigned short As[2][256 * 64];   // 64 KiB
    __shared__ unsigned short Bs[2][256 * 64];   // 64 KiB

    int tid = threadIdx.x;
    int lane = tid & 63, wave = tid >> 6;        // 8 waves
    int wm = wave >> 2, wn = wave & 3;           // 2M x 4N
    int l15 = lane & 15, quad = lane >> 4;
    int sx = l15 & 7;

    // XCD-panel swizzle: 32 row-blocks, 4 per XCD (grid = 8*4*NCOLB, %8==0)
    int f = blockIdx.x;
    int xcd = f & 7, slot = f >> 3;
    int rowblk = xcd * 4 + (slot & 3);           // 0..31
    int colblk = slot >> 2;
    int row0 = rowblk * 256;
    int col0 = colblk * 256;

    // staging: lane -> row +(lane>>3), swizzled source granule ((lane&7)^srow)*8
    int srow = lane >> 3;
    int gsw = ((lane & 7) ^ srow) * 8;
    const unsigned short* Ag = A + (size_t)(row0 + srow) * Cdim + gsw;
    const unsigned short* Bg = Bt + (size_t)(col0 + srow) * Cdim + gsw;

    // stage A-half h (rows h*128..+128) of k-offset kk into buf nb (2 GLDS)
    #define STG_A(h, kk, nb) do {                                               \
        unsigned short* L = &As[nb][((h) * 128 + wave * 8) * 64];               \
        GLDS(Ag + (size_t)((h) * 128 + wave * 8) * Cdim + (kk), L);             \
        GLDS(Ag + (size_t)((h) * 128 + 64 + wave * 8) * Cdim + (kk), L + 64 * 64); \
    } while (0)
    #define STG_B(h, kk, nb) do {                                               \
        unsigned short* L = &Bs[nb][((h) * 128 + wave * 8) * 64];               \
        GLDS(Bg + (size_t)((h) * 128 + wave * 8) * Cdim + (kk), L);             \
        GLDS(Bg + (size_t)((h) * 128 + 64 + wave * 8) * Cdim + (kk), L + 64 * 64); \
    } while (0)

    float4v acc[8][4] = {};
    short8 af0[8], af1[8];                       // A-frags kg=0 / kg=1, both live

    // prologue: stage all 4 halves of tile 0; one-time full drain
    STG_A(0, 0, 0); STG_A(1, 0, 0); STG_B(0, 0, 0); STG_B(1, 0, 0);
    asm volatile("s_waitcnt vmcnt(0)" ::: "memory");
    __builtin_amdgcn_s_barrier();

    int gc0 = (quad ^ sx) * 8;                   // frag col, kg=0
    int gc1 = ((4 + quad) ^ sx) * 8;             // frag col, kg=1

    #pragma unroll 1
    for (int t = 0; t < 16; ++t) {
        int b = t & 1, nb = b ^ 1;
        int kn = ((t + 1) & 15) * 64;            // wrap prefetch at tail (benign)
        const unsigned short* Asb = &As[b][0];
        const unsigned short* Bsb = &Bs[b][0];

        // ---- P0: nq=0, kg=0 : read af0[8] + bf(0,0) ; stage A0(t+1) ----
        {
            short8 bf[2];
            #pragma unroll
            for (int mi = 0; mi < 8; mi++)
                af0[mi] = *(const short8*)&Asb[(wm * 128 + mi * 16 + l15) * 64 + gc0];
            #pragma unroll
            for (int ni = 0; ni < 2; ni++)
                bf[ni] = *(const short8*)&Bsb[(wn * 64 + ni * 16 + l15) * 64 + gc0];
            STG_A(0, kn, nb);
            __builtin_amdgcn_s_barrier();
            asm volatile("s_waitcnt lgkmcnt(0)" ::: "memory");
            __builtin_amdgcn_sched_barrier(0);
            __builtin_amdgcn_s_setprio(1);
            #pragma unroll
            for (int mi = 0; mi < 8; mi++)
                #pragma unroll
                for (int ni = 0; ni < 2; ni++)
                    acc[mi][ni] = __builtin_amdgcn_mfma_f32_16x16x32_bf16(af0[mi], bf[ni], acc[mi][ni], 0, 0, 0);
            __builtin_amdgcn_s_setprio(0);
            __builtin_amdgcn_s_barrier();
        }
        // ---- P1: nq=0, kg=1 : read af1[8] + bf(0,1) ; stage A1(t+1) ; vmcnt(4) ----
        {
            short8 bf[2];
            #pragma unroll
            for (int mi = 0; mi < 8; mi++)
                af1[mi] = *(const short8*)&Asb[(wm * 128 + mi * 16 + l15) * 64 + gc1];
            #pragma unroll
            for (int ni = 0; ni < 2; ni++)
                bf[ni] = *(const short8*)&Bsb[(wn * 64 + ni * 16 + l15) * 64 + gc1];
            STG_A(1, kn, nb);
            asm volatile("s_waitcnt vmcnt(4)" ::: "memory");   // drains B1(t)
            __builtin_amdgcn_s_barrier();
            asm volatile("s_waitcnt lgkmcnt(0)" ::: "memory");
            __builtin_amdgcn_sched_barrier(0);
            __builtin_amdgcn_s_setprio(1);
            #pragma unroll
            for (int mi = 0; mi < 8; mi++)
                #pragma unroll
                for (int ni = 0; ni < 2; ni++)
                    acc[mi][ni] = __builtin_amdgcn_mfma_f32_16x16x32_bf16(af1[mi], bf[ni], acc[mi][ni], 0, 0, 0);
            __builtin_amdgcn_s_setprio(0);
            __builtin_amdgcn_s_barrier();
        }
        // ---- P2: nq=1, kg=1 : read bf(1,1) only ; stage B0(t+1) ----
        {
            short8 bf[2];
            #pragma unroll
            for (int ni = 0; ni < 2; ni++)
                bf[ni] = *(const short8*)&Bsb[(wn * 64 + 32 + ni * 16 + l15) * 64 + gc1];
            STG_B(0, kn, nb);
            __builtin_amdgcn_s_barrier();
            asm volatile("s_waitcnt lgkmcnt(0)" ::: "memory");
            __builtin_amdgcn_sched_barrier(0);
            __builtin_amdgcn_s_setprio(1);
            #pragma unroll
            for (int mi = 0; mi < 8; mi++)
                #pragma unroll
                for (int ni = 0; ni < 2; ni++)
                    acc[mi][2 + ni] = __builtin_amdgcn_mfma_f32_16x16x32_bf16(af1[mi], bf[ni], acc[mi][2 + ni], 0, 0, 0);
            __builtin_amdgcn_s_setprio(0);
            __builtin_amdgcn_s_barrier();
        }
        // ---- P3: nq=1, kg=0 : read bf(1,0) only ; stage B1(t+1) ; vmcnt(2) ----
        {
            short8 bf[2];
            #pragma unroll
            for (int ni = 0; ni < 2; ni++)
                bf[ni] = *(const short8*)&Bsb[(wn * 64 + 32 + ni * 16 + l15) * 64 + gc0];
            STG_B(1, kn, nb);
            asm volatile("s_waitcnt vmcnt(2)" ::: "memory");   // drains A0,A1,B0(t+1)
            __builtin_amdgcn_s_barrier();
            asm volatile("s_waitcnt lgkmcnt(0)" ::: "memory");
            __builtin_amdgcn_sched_barrier(0);
            __builtin_amdgcn_s_setprio(1);
            #pragma unroll
            for (int mi = 0; mi < 8; mi++)
                #pragma unroll
                for (int ni = 0; ni < 2; ni++)
                    acc[mi][2 + ni] = __builtin_amdgcn_mfma_f32_16x16x32_bf16(af0[mi], bf[ni], acc[mi][2 + ni], 0, 0, 0);
            __builtin_amdgcn_s_setprio(0);
            __builtin_amdgcn_s_barrier();
        }
    }
    // retire dangling wrap-prefetch DMAs before LDS goes away
    asm volatile("s_waitcnt vmcnt(0)" ::: "memory");
    #undef STG_A
    #undef STG_B

    // epilogue
    #pragma unroll
    for (int mi = 0; mi < 8; mi++) {
        #pragma unroll
        for (int nj = 0; nj < 4; nj++) {
            int colb = col0 + wn * 64 + nj * 16 + l15;
            int rowb = row0 + wm * 128 + mi * 16 + quad * 4;
            if (QKV) {
                int p = colb >> 10;          // 0=q 1=k 2=v
                int h = (colb & 1023) >> 6;
                int d = colb & 63;
                int b = rowb >> 11;
                int t = rowb & 2047;
                if (p == 2) {
                    ushort4 pk;
                    pk.x = f2b(acc[mi][nj][0] + bias[colb]);
                    pk.y = f2b(acc[mi][nj][1] + bias[colb]);
                    pk.z = f2b(acc[mi][nj][2] + bias[colb]);
                    pk.w = f2b(acc[mi][nj][3] + bias[colb]);
                    *(ushort4*)&vb[((size_t)(b * NH + h) * HD + d) * Tseq + t] = pk;
                } else {
                    unsigned short* dst = (p == 0) ? qb : kb;
                    #pragma unroll
                    for (int r = 0; r < 4; r++)
                        dst[((size_t)(b * NH + h) * Tseq + (t + r)) * HD + d] =
                            f2b(acc[mi][nj][r] + bias[colb]);
                }
            } else {
                #pragma unroll
                for (int r = 0; r < 4; r++)
                    out[(size_t)(rowb + r) * Cdim + colb] = acc[mi][nj][r] + bias[colb];
            }
        }
    }
}

// ---------------- bf16 MFMA GEMM (proj): 256x128 tile, triple-buffered ----------------
// r3 structure: counted vmcnt(6), stage t+2 while computing t. Proj keeps this
// (256-wide tiles would leave half the chip idle at N=1024).

template<bool QKV>
__global__ __launch_bounds__(512, 2) void gemm256(const unsigned short* __restrict__ A,
                                                  const unsigned short* __restrict__ Bt,
                                                  const float* __restrict__ bias,
                                                  unsigned short* __restrict__ qb,
                                                  unsigned short* __restrict__ kb,
                                                  unsigned short* __restrict__ vb,
                                                  float* __restrict__ out) {
    __shared__ unsigned short As[3][256 * 64];   // 96 KB
    __shared__ unsigned short Bs[3][128 * 64];   // 48 KB

    int tid = threadIdx.x;
    int lane = tid & 63, wave = tid >> 6;        // 8 waves
    int wm = wave >> 2, wn = wave & 3;           // 2M x 4N
    int l15 = lane & 15, quad = lane >> 4;
    int sx = l15 & 7;

    int f = blockIdx.x;
    int xcd = f & 7, slot = f >> 3;
    int rowblk = xcd * 4 + (slot & 3);           // 0..31
    int colblk = slot >> 2;
    int row0 = rowblk * 256;
    int col0 = colblk * 128;

    int srow = lane >> 3;
    int gsw = ((lane & 7) ^ srow) * 8;
    const unsigned short* Ag = A + (size_t)(row0 + wave * 32 + srow) * Cdim + gsw;
    const unsigned short* Bg = Bt + (size_t)(col0 + wave * 16 + srow) * Cdim + gsw;

    float4v acc[8][2] = {};

    #define STAGE256(kk, sb) do {                                              \
        unsigned short* Al = &As[sb][wave * 32 * 64];                          \
        unsigned short* Bl = &Bs[sb][wave * 16 * 64];                          \
        GLDS(Ag + (kk), Al);                                                   \
        GLDS(Ag + (kk) + (size_t)8  * Cdim, Al + 8 * 64);                      \
        GLDS(Ag + (kk) + (size_t)16 * Cdim, Al + 16 * 64);                     \
        GLDS(Ag + (kk) + (size_t)24 * Cdim, Al + 24 * 64);                     \
        GLDS(Bg + (kk), Bl);                                                   \
        GLDS(Bg + (kk) + (size_t)8  * Cdim, Bl + 8 * 64);                      \
    } while (0)

    STAGE256(0, 0);
    STAGE256(64, 1);
    asm volatile("s_waitcnt vmcnt(6)" ::: "memory");
    __builtin_amdgcn_s_barrier();

    int bc = 0, bp = 2;
    #pragma unroll 1
    for (int t = 0; t < 16; ++t) {
        int kpre = ((t + 2) & 15) * 64;
        STAGE256(kpre, bp);

        const unsigned short* Asb = &As[bc][0];
        const unsigned short* Bsb = &Bs[bc][0];
        #pragma unroll
        for (int kg = 0; kg < 2; kg++) {
            int gcol = ((kg * 4 + quad) ^ sx) * 8;
            short8 af[8], bf[2];
            #pragma unroll
            for (int mi = 0; mi < 8; mi++)
                af[mi] = *(const short8*)&Asb[(wm * 128 + mi * 16 + l15) * 64 + gcol];
            #pragma unroll
            for (int ni = 0; ni < 2; ni++)
                bf[ni] = *(const short8*)&Bsb[(wn * 32 + ni * 16 + l15) * 64 + gcol];
            __builtin_amdgcn_s_setprio(1);
            #pragma unroll
            for (int mi = 0; mi < 8; mi++)
                #pragma unroll
                for (int ni = 0; ni < 2; ni++)
                    acc[mi][ni] = __builtin_amdgcn_mfma_f32_16x16x32_bf16(af[mi], bf[ni], acc[mi][ni], 0, 0, 0);
            __builtin_amdgcn_s_setprio(0);
        }

        asm volatile("s_waitcnt vmcnt(6)" ::: "memory");
        __builtin_amdgcn_s_barrier();
        bc = (bc == 2) ? 0 : bc + 1;
        bp = (bp == 2) ? 0 : bp + 1;
    }
    asm volatile("s_waitcnt vmcnt(0)" ::: "memory");
    #undef STAGE256

    #pragma unroll
    for (int mi = 0; mi < 8; mi++) {
        #pragma unroll
        for (int ni = 0; ni < 2; ni++) {
            int colb = col0 + wn * 32 + ni * 16 + l15;
            int rowb = row0 + wm * 128 + mi * 16 + quad * 4;
            if (QKV) {
                int p = colb >> 10;
                int h = (colb & 1023) >> 6;
                int d = colb & 63;
                int b = rowb >> 11;
                int t = rowb & 2047;
                if (p == 2) {
                    ushort4 pk;
                    pk.x = f2b(acc[mi][ni][0] + bias[colb]);
                    pk.y = f2b(acc[mi][ni][1] + bias[colb]);
                    pk.z = f2b(acc[mi][ni][2] + bias[colb]);
                    pk.w = f2b(acc[mi][ni][3] + bias[colb]);
                    *(ushort4*)&vb[((size_t)(b * NH + h) * HD + d) * Tseq + t] = pk;
                } else {
                    unsigned short* dst = (p == 0) ? qb : kb;
                    #pragma unroll
                    for (int r = 0; r < 4; r++)
                        dst[((size_t)(b * NH + h) * Tseq + (t + r)) * HD + d] =
                            f2b(acc[mi][ni][r] + bias[colb]);
                }
            } else {
                #pragma unroll
                for (int r = 0; r < 4; r++)
                    out[(size_t)(rowb + r) * Cdim + colb] = acc[mi][ni][r] + bias[colb];
            }
        }
    }
}

// ---------------- flash attention (causal), bf16 MFMA ----------------
// 4-wave blocks (256 thr), q-tile = 128 rows (32/wave), 64-key windows,
// double-buffered K/V LDS with 2-phase pipeline; XOR-swizzled staging;
// S^T register trick; defer-rescale.

__global__ __launch_bounds__(256, 4) void attn_kernel(const unsigned short* __restrict__ qb,
                                                      const unsigned short* __restrict__ kb,
                                                      const unsigned short* __restrict__ vt,
                                                      unsigned short* __restrict__ yb) {
    __shared__ unsigned short Ks[2][64 * 64];   // [buf][key][64d], swizzled
    __shared__ unsigned short Vs[2][64 * 64];   // [buf][d][64key], swizzled

    int tid = threadIdx.x;
    int lane = tid & 63, wave = tid >> 6;      // 4 waves
    int l15 = lane & 15, quad = lane >> 4;
    int bh = blockIdx.x;
    int qt = 15 - blockIdx.y;

    const unsigned short* Qh = qb + (size_t)bh * Tseq * HD;
    const unsigned short* Kh = kb + (size_t)bh * Tseq * HD;
    const unsigned short* Vh = vt + (size_t)bh * HD * Tseq;
    int b = bh >> 4, h = bh & 15;
    const float cexp = 0.18033688011112042f;   // 0.125 * log2(e)

    int q0 = qt * 128;
    int rb0 = q0 + wave * 32;

    short8 qf[2][2];
    #pragma unroll
    for (int mi = 0; mi < 2; mi++)
        #pragma unroll
        for (int g = 0; g < 2; g++)
            qf[mi][g] = *(const short8*)(Qh + (size_t)(rb0 + mi * 16 + l15) * HD + g * 32 + quad * 8);

    int srow = lane >> 3;
    int scol = ((lane & 7) ^ srow) * 8;
    const unsigned short* Kg0 = Kh + (size_t)(wave * 16 + srow) * HD + scol;
    const unsigned short* Vg0 = Vh + (size_t)(wave * 16 + srow) * Tseq + scol;
    unsigned short* Kl0 = &Ks[0][wave * 1024];
    unsigned short* Vl0 = &Vs[0][wave * 1024];
    unsigned short* Kl1 = &Ks[1][wave * 1024];
    unsigned short* Vl1 = &Vs[1][wave * 1024];

    int sx = l15 & 7;
    int kx0 = (quad ^ sx) * 8;
    int kx1 = ((4 + quad) ^ sx) * 8;
    int qh_ = quad >> 1, ql_ = quad & 1;

    float4v ov[2][4] = {};
    float m[2]  = {-1e30f, -1e30f};
    float lp[2] = {0.f, 0.f};

    int nw = (q0 >> 6) + 2;

    GLDS(Kg0, Kl0);                GLDS(Kg0 + 8 * HD, Kl0 + 512);
    GLDS(Vg0, Vl0);                GLDS(Vg0 + 8 * Tseq, Vl0 + 512);
    __syncthreads();

    #pragma unroll 1
    for (int it = 0; it < nw; ++it) {
        int j0 = it << 6;

        if (it + 1 < nw) {
            int jn = j0 + 64;
            unsigned short* Kl = (it & 1) ? Kl0 : Kl1;
            unsigned short* Vl = (it & 1) ? Vl0 : Vl1;
            GLDS(Kg0 + (size_t)jn * HD, Kl);
            GLDS(Kg0 + (size_t)(jn + 8) * HD, Kl + 512);
            GLDS(Vg0 + jn, Vl);
            GLDS(Vg0 + 8 * Tseq + jn, Vl + 512);
        }

        if (j0 <= rb0 + 31) {
            const unsigned short* Kl = &Ks[it & 1][0];
            const unsigned short* Vl = &Vs[it & 1][0];

            float4v st[2][4];
            #pragma unroll
            for (int mi = 0; mi < 2; mi++)
                #pragma unroll
                for (int kg = 0; kg < 4; kg++)
                    st[mi][kg] = (float4v){0.f, 0.f, 0.f, 0.f};
            #pragma unroll
            for (int kg = 0; kg < 4; kg++) {
                int krow = kg * 1024 + l15 * 64;
                short8 kf0 = *(const short8*)&Kl[krow + kx0];
                short8 kf1 = *(const short8*)&Kl[krow + kx1];
                st[0][kg] = __builtin_amdgcn_mfma_f32_16x16x32_bf16(kf0, qf[0][0], st[0][kg], 0, 0, 0);
                st[0][kg] = __builtin_amdgcn_mfma_f32_16x16x32_bf16(kf1, qf[0][1], st[0][kg], 0, 0, 0);
                st[1][kg] = __builtin_amdgcn_mfma_f32_16x16x32_bf16(kf0, qf[1][0], st[1][kg], 0, 0, 0);
                st[1][kg] = __builtin_amdgcn_mfma_f32_16x16x32_bf16(kf1, qf[1][1], st[1][kg], 0, 0, 0);
            }

            if (j0 + 63 > rb0) {
                #pragma unroll
                for (int mi = 0; mi < 2; mi++) {
                    int qrow = rb0 + mi * 16 + l15;
                    #pragma unroll
                    for (int kg = 0; kg < 4; kg++) {
                        int keyb = j0 + kg * 16 + quad * 4;
                        #pragma unroll
                        for (int r = 0; r < 4; r++)
                            if (keyb + r > qrow) st[mi][kg][r] = -1e30f;
                    }
                }
            }

            short4v pf[2][4];
            #pragma unroll
            for (int mi = 0; mi < 2; mi++) {
                float mx = st[mi][0][0];
                #pragma unroll
                for (int kg = 0; kg < 4; kg++)
                    #pragma unroll
                    for (int r = 0; r < 4; r++)
                        mx = fmaxf(mx, st[mi][kg][r]);
                mx = fmaxf(mx, __shfl_xor(mx, 16));
                mx = fmaxf(mx, __shfl_xor(mx, 32));
                if (__any(mx > m[mi] + 16.0f)) {
                    float mn = fmaxf(m[mi], mx);
                    float alv = __builtin_amdgcn_exp2f((m[mi] - mn) * cexp);
                    m[mi] = mn;
                    lp[mi] *= alv;
                    float ar_[4];
                    #pragma unroll
                    for (int r = 0; r < 4; r++)
                        ar_[r] = __shfl(alv, quad * 4 + r);
                    #pragma unroll
                    for (int dg = 0; dg < 4; dg++)
                        #pragma unroll
                        for (int r = 0; r < 4; r++)
                            ov[mi][dg][r] *= ar_[r];
                }
                float mc = -m[mi] * cexp;
                float sum = 0.f;
                #pragma unroll
                for (int kg = 0; kg < 4; kg++) {
                    float p0 = __builtin_amdgcn_exp2f(__builtin_fmaf(st[mi][kg][0], cexp, mc));
                    float p1 = __builtin_amdgcn_exp2f(__builtin_fmaf(st[mi][kg][1], cexp, mc));
                    float p2 = __builtin_amdgcn_exp2f(__builtin_fmaf(st[mi][kg][2], cexp, mc));
                    float p3 = __builtin_amdgcn_exp2f(__builtin_fmaf(st[mi][kg][3], cexp, mc));
                    sum += (p0 + p1) + (p2 + p3);
                    union { unsigned u[2]; short4v s; } pk_;
                    pk_.u[0] = pk2bf(p0, p1);
                    pk_.u[1] = pk2bf(p2, p3);
                    pf[mi][kg] = pk_.s;
                }
                lp[mi] += sum;
            }

            #pragma unroll
            for (int kg = 0; kg < 4; kg++) {
                int vx = (((kg * 2 + qh_) ^ sx) << 3) + ql_ * 4;
                #pragma unroll
                for (int dg = 0; dg < 4; dg++) {
                    short4v vf = *(const short4v*)&Vl[dg * 1024 + l15 * 64 + vx];
                    ov[0][dg] = __builtin_amdgcn_mfma_f32_16x16x16bf16_1k(pf[0][kg], vf, ov[0][dg], 0, 0, 0);
                    ov[1][dg] = __builtin_amdgcn_mfma_f32_16x16x16bf16_1k(pf[1][kg], vf, ov[1][dg], 0, 0, 0);
                }
            }
        }

        __syncthreads();
    }

    #pragma unroll
    for (int mi = 0; mi < 2; mi++) {
        float lf = lp[mi];
        lf += __shfl_xor(lf, 16);
        lf += __shfl_xor(lf, 32);
        float rinv[4];
        #pragma unroll
        for (int r = 0; r < 4; r++)
            rinv[r] = 1.0f / __shfl(lf, quad * 4 + r);
        #pragma unroll
        for (int dg = 0; dg < 4; dg++)
            #pragma unroll
            for (int r = 0; r < 4; r++) {
                int t = rb0 + mi * 16 + quad * 4 + r;
                yb[((size_t)b * Tseq + t) * Cdim + h * HD + dg * 16 + l15] =
                    f2b(ov[mi][dg][r] * rinv[r]);
            }
    }
}

extern "C" void kernel_launch(void* const* d_in, const int* in_sizes, int n_in,
                              void* d_out, int out_size, void* d_ws, size_t ws_size,
                              hipStream_t stream) {
    const float* x  = (const float*)d_in[0];
    const float* Wa = (const float*)d_in[1];
    const float* ba = (const float*)d_in[2];
    const float* Wp = (const float*)d_in[3];
    const float* bp = (const float*)d_in[4];
    float* out = (float*)d_out;

    unsigned short* ws = (unsigned short*)d_ws;
    unsigned short* xb  = ws;                          // 8192*1024
    unsigned short* Wat = xb  + (size_t)Mrows * Cdim;  // 3072*1024
    unsigned short* Wpt = Wat + (size_t)N3C * Cdim;    // 1024*1024
    unsigned short* qb  = Wpt + (size_t)Cdim * Cdim;   // [bh][T][HD]
    unsigned short* kb  = qb  + (size_t)Bsz * NH * Tseq * HD;   // [bh][T][HD]
    unsigned short* vb  = kb  + (size_t)Bsz * NH * Tseq * HD;   // [bh][HD][T]  (transposed)
    unsigned short* yb  = vb  + (size_t)Bsz * NH * Tseq * HD;

    int nx = Mrows * Cdim;
    cast_kernel<<<nx / 4 / 256, 256, 0, stream>>>(x, xb, nx);
    transpose_cast<<<dim3(N3C / 32, Cdim / 32), 256, 0, stream>>>(Wa, Wat, Cdim, N3C);
    transpose_cast<<<dim3(Cdim / 32, Cdim / 32), 256, 0, stream>>>(Wp, Wpt, Cdim, Cdim);

    // QKV: 32 rowblks x 12 colblks (256x256 tiles) = 384 blocks, 8-phase kernel
    gemm8p<true><<<384, 512, 0, stream>>>(xb, Wat, ba, qb, kb, vb, nullptr);

    attn_kernel<<<dim3(Bsz * NH, 16), 256, 0, stream>>>(qb, kb, vb, yb);

    // proj: 32 rowblks x 8 colblks (256x128 tiles) = 256 blocks
    gemm256<false><<<256, 512, 0, stream>>>(yb, Wpt, bp, nullptr, nullptr, nullptr, out);
}